// Round 9
// baseline (225.019 us; speedup 1.0000x reference)
//
#include <hip/hip_runtime.h>
#include <math.h>

// Problem constants: B=1024, N=200, E=128, fp32.
constexpr int Bc = 1024;
constexpr int Nc = 200;
constexpr int Ec = 128;

// R9: cache-policy split. Ledger: nt-on-everything (R5/R8, 221us) beats
// plain-on-everything (R4/R7, 236us) because the harness re-poisons a ~400MB
// arena each iteration and a 210MB plain-read working set thrashes the 256MB
// MALL -> half-density scattered miss stream. But nt also discards all cache
// help (FETCH 106->210MB). Split: m (100MB, fits MALL with room to spare once
// m_c stops competing for allocation) -> PLAIN loads; m_c -> nt stream. If m
// stays resident, the two 105MB halves are served concurrently from MALL and
// DRAM. One-bit diff from R8; FETCH_SIZE adjudicates (~110MB = m hot,
// ~210MB = m cold/neutral).
constexpr int ROWS    = 5;                 // rows per 32-lane group
constexpr int GROUPS  = 8;                 // 256 threads / 32
constexpr int NSPLIT  = 5;                 // blocks per batch (5*40 = 200 rows)

typedef float v4f __attribute__((ext_vector_type(4)));

__global__ __launch_bounds__(256, 4) void dist_phase(
    const float* __restrict__ q,      // (B,E)
    const float* __restrict__ q_p,    // (B,E)
    const float* __restrict__ m,      // (B,N,E)
    const float* __restrict__ m_c,    // (B,N,E)
    const float* __restrict__ A1,     // (E)
    const float* __restrict__ A2,     // (E)
    const float* __restrict__ biases, // (B,N)
    const float* __restrict__ mask,   // (B,N)
    float* __restrict__ xs_ws,        // (B,N) softmax arguments -> workspace
    float* __restrict__ out)          // (B,N) out_dist*mask (scaled later by k2)
{
    const int j    = blockIdx.x;     // 0..NSPLIT-1  (which 40-row slice)
    const int b    = blockIdx.y;     // batch
    const int tid  = threadIdx.x;
    const int hw   = tid >> 5;       // group id 0..7
    const int lane = tid & 31;
    const int e0   = lane * 4;

    const int n0 = j * (GROUPS * ROWS) + hw * ROWS;

    // Per-lane chunks of q, q_p, A1, A2 (small, reused across blocks: cached).
    const v4f qv  = *reinterpret_cast<const v4f*>(q   + (size_t)b * Ec + e0);
    const v4f qpv = *reinterpret_cast<const v4f*>(q_p + (size_t)b * Ec + e0);
    const v4f a1v = *reinterpret_cast<const v4f*>(A1  + e0);
    const v4f a2v = *reinterpret_cast<const v4f*>(A2  + e0);

    const float* mb  = m   + (size_t)b * Nc * Ec;
    const float* mcb = m_c + (size_t)b * Nc * Ec;

    // m: PLAIN loads (candidate for MALL residency); m_c: nt stream.
    v4f mv[ROWS], mcv[ROWS];
#pragma unroll
    for (int r = 0; r < ROWS; ++r) {
        mv[r]  = *reinterpret_cast<const v4f*>(mb  + (size_t)(n0 + r) * Ec + e0);
        mcv[r] = __builtin_nontemporal_load(
                     reinterpret_cast<const v4f*>(mcb + (size_t)(n0 + r) * Ec + e0));
    }
    // Fence: no load may sink below this point -> full 10-deep burst issued.
    asm volatile("" ::: "memory");

    float s_att[ROWS], s_out[ROWS];
#pragma unroll
    for (int r = 0; r < ROWS; ++r) {
        // Per-row pin (kept from R8; established neutral, keeps code stable).
        asm volatile("" : "+v"(mv[r]), "+v"(mcv[r]));
        float sa = 0.f, so = 0.f;
#pragma unroll
        for (int c = 0; c < 4; ++c) {
            float t1 = (qv[c]  - mv[r][c])  * a1v[c];  sa = fmaf(t1, t1, sa);
            float t2 = (qpv[c] - mv[r][c])  * a2v[c];  sa = fmaf(t2, t2, sa);
            float u1 = (qv[c]  - mcv[r][c]) * a1v[c];  so = fmaf(u1, u1, so);
            float u2 = (qpv[c] - mcv[r][c]) * a2v[c];  so = fmaf(u2, u2, so);
        }
        s_att[r] = sa;
        s_out[r] = so;
    }

    // 10 interleaved shuffle-reduce chains (xor <=16 stays in the 32-lane half).
#pragma unroll
    for (int off = 16; off > 0; off >>= 1) {
#pragma unroll
        for (int r = 0; r < ROWS; ++r) {
            s_att[r] += __shfl_xor(s_att[r], off);
            s_out[r] += __shfl_xor(s_out[r], off);
        }
    }

    if (lane == 0) {
#pragma unroll
        for (int r = 0; r < ROWS; ++r) {
            const int n = n0 + r;
            const float bb = biases[(size_t)b * Nc + n];
            const float mk = mask[(size_t)b * Nc + n];
            // att_dist = d1 + bias + d2 + bias = s_att + 2*bias
            xs_ws[(size_t)b * Nc + n] = -(s_att[r] + 2.f * bb) * mk;
            out  [(size_t)b * Nc + n] =  (s_out[r] + 2.f * bb) * mk;
        }
    }
}

// One 256-thread block per batch: softmax over the 200 entries, scale os.
__global__ __launch_bounds__(256, 4) void softmax_phase(
    const float* __restrict__ xs_ws,  // (B,N)
    float* __restrict__ out)          // (B,N) in: os, out: os * softmax
{
    const int b   = blockIdx.x;
    const int tid = threadIdx.x;

    __shared__ float red_s[8];  // 4 max + 4 sum

    const float x  = (tid < Nc) ? xs_ws[(size_t)b * Nc + tid] : -INFINITY;
    const float os = (tid < Nc) ? out  [(size_t)b * Nc + tid] : 0.f;

    // max
    float wmax = x;
#pragma unroll
    for (int off = 32; off > 0; off >>= 1)
        wmax = fmaxf(wmax, __shfl_xor(wmax, off));
    if ((tid & 63) == 0) red_s[tid >> 6] = wmax;
    __syncthreads();
    const float gmax = fmaxf(fmaxf(red_s[0], red_s[1]), fmaxf(red_s[2], red_s[3]));

    // sum of exp
    const float ex = (tid < Nc) ? expf(x - gmax) : 0.f;
    float wsum = ex;
#pragma unroll
    for (int off = 32; off > 0; off >>= 1)
        wsum += __shfl_xor(wsum, off);
    if ((tid & 63) == 0) red_s[4 + (tid >> 6)] = wsum;
    __syncthreads();
    const float gsum = (red_s[4] + red_s[5]) + (red_s[6] + red_s[7]);

    if (tid < Nc) {
        out[(size_t)b * Nc + tid] = os * (ex / gsum);
    }
}

extern "C" void kernel_launch(void* const* d_in, const int* in_sizes, int n_in,
                              void* d_out, int out_size, void* d_ws, size_t ws_size,
                              hipStream_t stream) {
    const float* q      = (const float*)d_in[0];
    const float* q_p    = (const float*)d_in[1];
    const float* m      = (const float*)d_in[2];
    const float* m_c    = (const float*)d_in[3];
    const float* A1     = (const float*)d_in[4];
    const float* A2     = (const float*)d_in[5];
    const float* biases = (const float*)d_in[6];
    const float* mask   = (const float*)d_in[7];
    float* out   = (float*)d_out;
    float* xs_ws = (float*)d_ws;     // needs B*N*4 = 800 KB of workspace

    dim3 grid1(NSPLIT, Bc, 1);
    dist_phase<<<grid1, 256, 0, stream>>>(q, q_p, m, m_c, A1, A2, biases, mask,
                                          xs_ws, out);
    softmax_phase<<<Bc, 256, 0, stream>>>(xs_ws, out);
}

// Round 10
// 221.700 us; speedup vs baseline: 1.0150x; 1.0150x over previous
//
#include <hip/hip_runtime.h>
#include <math.h>

// Problem constants: B=1024, N=200, E=128, fp32.
constexpr int Bc = 1024;
constexpr int Nc = 200;
constexpr int Ec = 128;

// R10: instruction-level MLP. Ledger: all-nt is the proven cache policy
// (R5/R8=221 vs plain=236, split=225); every COMPILER-level scheduling nudge
// (value-pins, fences, reg-dbuf) left VGPR at 36 => 2-3 loads in flight/wave.
// Little's law with the measured 3.5 TB/s: loaded-system latency ~3-4us needs
// ~75-100KB in flight/CU; we carry ~50KB. Fix: ONE volatile asm issuing all
// 10 global_load_dwordx4 ... nt (shared base addr per array, rows via
// offset:0..2048), then per-row consumption behind manual
// s_waitcnt vmcnt(8/6/4/2/0) + sched_barrier(0) (rule #18: barrier stops
// hipcc hoisting FMAs above the wait). q/qp/A are value-pinned (=> their
// waitcnt lands) BEFORE the burst so no stray vmcnt(0) drains our counter.
constexpr int ROWS    = 5;                 // rows per 32-lane group
constexpr int GROUPS  = 8;                 // 256 threads / 32
constexpr int NSPLIT  = 5;                 // blocks per batch (5*40 = 200 rows)

typedef float v4f __attribute__((ext_vector_type(4)));

__global__ __launch_bounds__(256) void dist_phase(
    const float* __restrict__ q,      // (B,E)
    const float* __restrict__ q_p,    // (B,E)
    const float* __restrict__ m,      // (B,N,E)
    const float* __restrict__ m_c,    // (B,N,E)
    const float* __restrict__ A1,     // (E)
    const float* __restrict__ A2,     // (E)
    const float* __restrict__ biases, // (B,N)
    const float* __restrict__ mask,   // (B,N)
    float* __restrict__ xs_ws,        // (B,N) softmax arguments -> workspace
    float* __restrict__ out)          // (B,N) out_dist*mask (scaled later by k2)
{
    const int j    = blockIdx.x;     // 0..NSPLIT-1  (which 40-row slice)
    const int b    = blockIdx.y;     // batch
    const int tid  = threadIdx.x;
    const int hw   = tid >> 5;       // group id 0..7
    const int lane = tid & 31;
    const int e0   = lane * 4;

    const int n0 = j * (GROUPS * ROWS) + hw * ROWS;

    v4f qv  = *reinterpret_cast<const v4f*>(q   + (size_t)b * Ec + e0);
    v4f qpv = *reinterpret_cast<const v4f*>(q_p + (size_t)b * Ec + e0);
    v4f a1v = *reinterpret_cast<const v4f*>(A1  + e0);
    v4f a2v = *reinterpret_cast<const v4f*>(A2  + e0);

    // Row-0 base addresses; rows r at +512B steps (Ec*4), imm offset:512*r.
    const float* maddr  = m   + (size_t)b * Nc * Ec + (size_t)n0 * Ec + e0;
    const float* mcaddr = m_c + (size_t)b * Nc * Ec + (size_t)n0 * Ec + e0;

    // Drain the q/qp/A loads NOW (their compiler waitcnt lands here), so the
    // compiler has no pending vmem of its own across our hand-counted region.
    asm volatile("" : "+v"(qv), "+v"(qpv), "+v"(a1v), "+v"(a2v));

    // 10-deep nt burst: issue order m0,mc0,m1,mc1,... so vmcnt(8-2r) covers
    // exactly rows 0..r.
    v4f m0, c0, m1, c1, m2, c2, m3, c3, m4, c4;
    asm volatile(
        "global_load_dwordx4 %[d0], %[ma],  off nt\n\t"
        "global_load_dwordx4 %[e0], %[mc],  off nt\n\t"
        "global_load_dwordx4 %[d1], %[ma],  off offset:512 nt\n\t"
        "global_load_dwordx4 %[e1], %[mc],  off offset:512 nt\n\t"
        "global_load_dwordx4 %[d2], %[ma],  off offset:1024 nt\n\t"
        "global_load_dwordx4 %[e2], %[mc],  off offset:1024 nt\n\t"
        "global_load_dwordx4 %[d3], %[ma],  off offset:1536 nt\n\t"
        "global_load_dwordx4 %[e3], %[mc],  off offset:1536 nt\n\t"
        "global_load_dwordx4 %[d4], %[ma],  off offset:2048 nt\n\t"
        "global_load_dwordx4 %[e4], %[mc],  off offset:2048 nt"
        : [d0]"=v"(m0), [e0]"=v"(c0), [d1]"=v"(m1), [e1]"=v"(c1),
          [d2]"=v"(m2), [e2]"=v"(c2), [d3]"=v"(m3), [e3]"=v"(c3),
          [d4]"=v"(m4), [e4]"=v"(c4)
        : [ma]"v"(maddr), [mc]"v"(mcaddr)
        : "memory");

    float s_att[ROWS], s_out[ROWS];
    v4f mr[ROWS] = {m0, m1, m2, m3, m4};
    v4f cr[ROWS] = {c0, c1, c2, c3, c4};
    // NOTE: mr/cr are fully unrolled below (static indices only, rule #20).
#define ROWBODY(r, cnt)                                                     \
    {                                                                       \
        asm volatile("s_waitcnt vmcnt(" #cnt ")" ::: "memory");             \
        __builtin_amdgcn_sched_barrier(0);                                  \
        float sa = 0.f, so = 0.f;                                           \
        _Pragma("unroll")                                                   \
        for (int c = 0; c < 4; ++c) {                                       \
            float t1 = (qv[c]  - mr[r][c]) * a1v[c];  sa = fmaf(t1, t1, sa);\
            float t2 = (qpv[c] - mr[r][c]) * a2v[c];  sa = fmaf(t2, t2, sa);\
            float u1 = (qv[c]  - cr[r][c]) * a1v[c];  so = fmaf(u1, u1, so);\
            float u2 = (qpv[c] - cr[r][c]) * a2v[c];  so = fmaf(u2, u2, so);\
        }                                                                   \
        s_att[r] = sa;                                                      \
        s_out[r] = so;                                                      \
    }
    ROWBODY(0, 8)
    ROWBODY(1, 6)
    ROWBODY(2, 4)
    ROWBODY(3, 2)
    ROWBODY(4, 0)
#undef ROWBODY

    // 10 interleaved shuffle-reduce chains (xor <=16 stays in the 32-lane half).
#pragma unroll
    for (int off = 16; off > 0; off >>= 1) {
#pragma unroll
        for (int r = 0; r < ROWS; ++r) {
            s_att[r] += __shfl_xor(s_att[r], off);
            s_out[r] += __shfl_xor(s_out[r], off);
        }
    }

    if (lane == 0) {
#pragma unroll
        for (int r = 0; r < ROWS; ++r) {
            const int n = n0 + r;
            const float bb = biases[(size_t)b * Nc + n];
            const float mk = mask[(size_t)b * Nc + n];
            // att_dist = d1 + bias + d2 + bias = s_att + 2*bias
            xs_ws[(size_t)b * Nc + n] = -(s_att[r] + 2.f * bb) * mk;
            out  [(size_t)b * Nc + n] =  (s_out[r] + 2.f * bb) * mk;
        }
    }
}

// One 256-thread block per batch: softmax over the 200 entries, scale os.
__global__ __launch_bounds__(256, 4) void softmax_phase(
    const float* __restrict__ xs_ws,  // (B,N)
    float* __restrict__ out)          // (B,N) in: os, out: os * softmax
{
    const int b   = blockIdx.x;
    const int tid = threadIdx.x;

    __shared__ float red_s[8];  // 4 max + 4 sum

    const float x  = (tid < Nc) ? xs_ws[(size_t)b * Nc + tid] : -INFINITY;
    const float os = (tid < Nc) ? out  [(size_t)b * Nc + tid] : 0.f;

    // max
    float wmax = x;
#pragma unroll
    for (int off = 32; off > 0; off >>= 1)
        wmax = fmaxf(wmax, __shfl_xor(wmax, off));
    if ((tid & 63) == 0) red_s[tid >> 6] = wmax;
    __syncthreads();
    const float gmax = fmaxf(fmaxf(red_s[0], red_s[1]), fmaxf(red_s[2], red_s[3]));

    // sum of exp
    const float ex = (tid < Nc) ? expf(x - gmax) : 0.f;
    float wsum = ex;
#pragma unroll
    for (int off = 32; off > 0; off >>= 1)
        wsum += __shfl_xor(wsum, off);
    if ((tid & 63) == 0) red_s[4 + (tid >> 6)] = wsum;
    __syncthreads();
    const float gsum = (red_s[4] + red_s[5]) + (red_s[6] + red_s[7]);

    if (tid < Nc) {
        out[(size_t)b * Nc + tid] = os * (ex / gsum);
    }
}

extern "C" void kernel_launch(void* const* d_in, const int* in_sizes, int n_in,
                              void* d_out, int out_size, void* d_ws, size_t ws_size,
                              hipStream_t stream) {
    const float* q      = (const float*)d_in[0];
    const float* q_p    = (const float*)d_in[1];
    const float* m      = (const float*)d_in[2];
    const float* m_c    = (const float*)d_in[3];
    const float* A1     = (const float*)d_in[4];
    const float* A2     = (const float*)d_in[5];
    const float* biases = (const float*)d_in[6];
    const float* mask   = (const float*)d_in[7];
    float* out   = (float*)d_out;
    float* xs_ws = (float*)d_ws;     // needs B*N*4 = 800 KB of workspace

    dim3 grid1(NSPLIT, Bc, 1);
    dist_phase<<<grid1, 256, 0, stream>>>(q, q_p, m, m_c, A1, A2, biases, mask,
                                          xs_ws, out);
    softmax_phase<<<Bc, 256, 0, stream>>>(xs_ws, out);
}